// Round 6
// baseline (278.839 us; speedup 1.0000x reference)
//
#include <hip/hip_runtime.h>
#include <hip/hip_bf16.h>

typedef __attribute__((ext_vector_type(8))) short bf16x8;
typedef __attribute__((ext_vector_type(4))) float f32x4;

#define B_  512
#define N_  256
#define SD_ 1024
#define HD_ 512
#define AD_ 256

__device__ __forceinline__ unsigned short f2bf(float f) {
    unsigned int u = __float_as_uint(f);
    unsigned int r = (u + 0x7FFFu + ((u >> 16) & 1u)) >> 16;
    return (unsigned short)r;
}

// ---------------------------------------------------------------------------
// K0: pack Wh (AD x HD, f32, row-major) into bf16 B-fragment layout for
// mfma_f32_16x16x32_bf16. Fragment (ct, ks): 64 lanes x 8 bf16 contiguous.
// B[k][col] = Wh[col][k];  col = ct*16 + (lane&15), k = ks*32 + (lane>>4)*8 + i
__global__ void k0_pack(const float* __restrict__ Wh, unsigned short* __restrict__ whp) {
    int g = blockIdx.x * 256 + threadIdx.x;
    int ct  = g >> 10;
    int rem = g & 1023;
    int ks  = rem >> 6;
    int l   = rem & 63;
    int a   = ct * 16 + (l & 15);
    int kb  = ks * 32 + (l >> 4) * 8;
    const float* src = Wh + (size_t)a * HD_ + kb;
    float4 v0 = *(const float4*)(src);
    float4 v1 = *(const float4*)(src + 4);
    bf16x8 o;
    o[0] = (short)f2bf(v0.x); o[1] = (short)f2bf(v0.y);
    o[2] = (short)f2bf(v0.z); o[3] = (short)f2bf(v0.w);
    o[4] = (short)f2bf(v1.x); o[5] = (short)f2bf(v1.y);
    o[6] = (short)f2bf(v1.z); o[7] = (short)f2bf(v1.w);
    ((bf16x8*)whp)[g] = o;
}

// ---------------------------------------------------------------------------
// K1: 2 b's per block, 512 threads. sp = state@Ws^T + bs (coalesced Ws reads),
// sn = max(||sp||,eps).
__global__ __launch_bounds__(512) void k1_proj(
    const float* __restrict__ state, const float* __restrict__ Ws,
    const float* __restrict__ bs,
    float* __restrict__ sn, float* __restrict__ spv)
{
    __shared__ float st[2][SD_];
    __shared__ float spl[2][AD_];
    __shared__ float red[2][AD_];
    int tid = threadIdx.x, lane = tid & 63, w = tid >> 6;
    int b0 = blockIdx.x * 2;
    ((float4*)st)[tid] = ((const float4*)(state + (size_t)b0 * SD_))[tid];
    __syncthreads();
    float4 s0[4], s1[4];
    #pragma unroll
    for (int seg = 0; seg < 4; ++seg) {
        s0[seg] = *(const float4*)&st[0][seg * 256 + lane * 4];
        s1[seg] = *(const float4*)&st[1][seg * 256 + lane * 4];
    }
    #pragma unroll 2
    for (int i = 0; i < 32; ++i) {
        int a = w * 32 + i;
        const float4* wr = (const float4*)(Ws + (size_t)a * SD_);
        float p0 = 0.f, p1 = 0.f;
        #pragma unroll
        for (int seg = 0; seg < 4; ++seg) {
            float4 wv = wr[seg * 64 + lane];
            p0 += wv.x * s0[seg].x + wv.y * s0[seg].y + wv.z * s0[seg].z + wv.w * s0[seg].w;
            p1 += wv.x * s1[seg].x + wv.y * s1[seg].y + wv.z * s1[seg].z + wv.w * s1[seg].w;
        }
        #pragma unroll
        for (int d = 1; d < 64; d <<= 1) { p0 += __shfl_xor(p0, d); p1 += __shfl_xor(p1, d); }
        if (lane == 0) {
            float bsa = bs[a];
            spl[0][a] = p0 + bsa;
            spl[1][a] = p1 + bsa;
        }
    }
    __syncthreads();
    int tb = tid >> 8, t = tid & 255;
    float sv = spl[tb][t];
    spv[(size_t)(b0 + tb) * AD_ + t] = sv;
    red[tb][t] = sv * sv;
    __syncthreads();
    for (int s = 128; s > 0; s >>= 1) { if (t < s) red[tb][t] += red[tb][t + s]; __syncthreads(); }
    if (t == 0) sn[b0 + tb] = fmaxf(sqrtf(red[tb][0]), 1e-8f);
}

// ---------------------------------------------------------------------------
// K2 fused: one block per b (512 threads, 8 waves), 2 blocks/CU, 128 VGPR.
// Coalesced staging; numerator and norm both from the hp MFMA accumulators.
// REGISTER DISCIPLINE (R4/R5 lesson): nothing besides acc may be live across
// the norm phase; the mc=1 chunk-0 loads are issued only AFTER the shuffle
// loop (acc dead), overlapping the sc/softmax barriers instead of norm VALU.
__device__ __forceinline__ void stage_tile(unsigned short* buf, const float4* v,
                                           int rr, int cg) {
    #pragma unroll
    for (int j = 0; j < 8; ++j) {
        int row = j * 16 + rr;
        float4 x = v[j];
        ushort4 u;
        u.x = f2bf(x.x); u.y = f2bf(x.y); u.z = f2bf(x.z); u.w = f2bf(x.w);
        *(ushort4*)((char*)buf + row * 256 + ((cg * 8) ^ ((row & 7) << 4))) = u;
    }
}

__global__ __launch_bounds__(512, 2) void k2_fused(
    const float* __restrict__ hints, const unsigned short* __restrict__ whp,
    const float* __restrict__ spv, const float* __restrict__ sn,
    const float* __restrict__ bh, float* __restrict__ out)
{
    __shared__ __align__(16) char smem[78848];
    unsigned short* A_bf0 = (unsigned short*)smem;            // 32KB
    unsigned short* A_bf1 = (unsigned short*)(smem + 32768);  // 32KB
    float* sp_lds  = (float*)(smem + 65536);                  // 1KB
    float* bh_lds  = (float*)(smem + 66560);                  // 1KB
    float* norm2p  = (float*)(smem + 67584);                  // 4KB
    float* nump    = (float*)(smem + 71680);                  // 4KB
    float* sc      = (float*)(smem + 75776);                  // 1KB
    float* red     = (float*)(smem + 76800);                  // 1KB
    float* wsm     = (float*)(smem + 77824);                  // 1KB
    float* scratch = (float*)smem;                            // epilogue alias

    int tid = threadIdx.x, lane = tid & 63, w = tid >> 6;
    int b = blockIdx.x;
    const float* hb = hints + (size_t)b * N_ * HD_;
    if (tid < 64) ((float4*)sp_lds)[tid] = ((const float4*)(spv + (size_t)b * AD_))[tid];
    else if (tid < 128) ((float4*)bh_lds)[tid - 64] = ((const float4*)bh)[tid - 64];
    float snb = sn[b];
    int rr = tid >> 5;        // row sub-index (0..15)
    int cg = tid & 31;        // 16B col-group within 128-col chunk
    int cl = lane & 15;
    const float* hrow = hb + (size_t)rr * HD_ + cg * 4;
    __syncthreads();
    float bh0 = bh_lds[(2 * w + 0) * 16 + cl];
    float bh1 = bh_lds[(2 * w + 1) * 16 + cl];
    float sp0 = sp_lds[(2 * w + 0) * 16 + cl];
    float sp1 = sp_lds[(2 * w + 1) * 16 + cl];

    float4 v[8];
    #pragma unroll
    for (int j = 0; j < 8; ++j)               // mc=0, chunk 0
        v[j] = *(const float4*)(hrow + (size_t)(j * 16) * HD_);

    for (int mc = 0; mc < 2; ++mc) {
        f32x4 acc[8][2];
        #pragma unroll
        for (int mf = 0; mf < 8; ++mf) {
            acc[mf][0] = (f32x4){0.f, 0.f, 0.f, 0.f};
            acc[mf][1] = (f32x4){0.f, 0.f, 0.f, 0.f};
        }
        stage_tile(A_bf0, v, rr, cg);
        __syncthreads();

        for (int kc = 0; kc < 4; ++kc) {
            // issue next chunk's loads early (T14: hide HBM under MFMA)
            if (kc < 3) {
                #pragma unroll
                for (int j = 0; j < 8; ++j)
                    v[j] = *(const float4*)(hrow + (size_t)(mc * 128 + j * 16) * HD_ + (kc + 1) * 128);
            }
            const unsigned short* Ab = (kc & 1) ? A_bf1 : A_bf0;
            int kc4 = kc * 4;
            #pragma unroll
            for (int ks = 0; ks < 4; ++ks) {
                bf16x8 bfr0 = ((const bf16x8*)whp)[((2 * w + 0) * 16 + kc4 + ks) * 64 + lane];
                bf16x8 bfr1 = ((const bf16x8*)whp)[((2 * w + 1) * 16 + kc4 + ks) * 64 + lane];
                #pragma unroll
                for (int mf = 0; mf < 8; ++mf) {
                    int r = mf * 16 + cl;
                    bf16x8 afr = *(const bf16x8*)((const char*)Ab + r * 256 +
                                 ((ks * 64 + (lane >> 4) * 16) ^ ((r & 7) << 4)));
                    acc[mf][0] = __builtin_amdgcn_mfma_f32_16x16x32_bf16(afr, bfr0, acc[mf][0], 0, 0, 0);
                    acc[mf][1] = __builtin_amdgcn_mfma_f32_16x16x32_bf16(afr, bfr1, acc[mf][1], 0, 0, 0);
                }
            }
            if (kc < 3) stage_tile((kc & 1) ? A_bf0 : A_bf1, v, rr, cg);
            __syncthreads();
        }

        // norm2 + numerator from acc. C layout: col = ct*16+cl, row = mf*16+(lane>>4)*4+r
        #pragma unroll
        for (int mf = 0; mf < 8; ++mf) {
            #pragma unroll
            for (int r = 0; r < 4; ++r) {
                float h0 = acc[mf][0][r] + bh0;
                float h1 = acc[mf][1][r] + bh1;
                float vv = h0 * h0 + h1 * h1;
                float uu = sp0 * h0 + sp1 * h1;
                vv += __shfl_xor(vv, 1); uu += __shfl_xor(uu, 1);
                vv += __shfl_xor(vv, 2); uu += __shfl_xor(uu, 2);
                vv += __shfl_xor(vv, 4); uu += __shfl_xor(uu, 4);
                vv += __shfl_xor(vv, 8); uu += __shfl_xor(uu, 8);
                if (cl == 0) {
                    int idx = w * 128 + mf * 16 + (lane >> 4) * 4 + r;
                    norm2p[idx] = vv;
                    nump[idx]   = uu;
                }
            }
        }
        // acc is DEAD here. Now (mc==0 only) issue mc=1 chunk-0 loads; they
        // fly under the sc compute + barriers + stage below.
        if (mc == 0) {
            #pragma unroll
            for (int j = 0; j < 8; ++j)
                v[j] = *(const float4*)(hrow + (size_t)(128 + j * 16) * HD_);
        }
        __syncthreads();
        if (tid < 128) {
            float n2 = 0.f, nm = 0.f;
            #pragma unroll
            for (int ww = 0; ww < 8; ++ww) {
                n2 += norm2p[ww * 128 + tid];
                nm += nump[ww * 128 + tid];
            }
            float hn = fmaxf(sqrtf(n2), 1e-8f);
            sc[mc * 128 + tid] = nm / (snb * hn);
        }
        __syncthreads();
    }

    // softmax over sc[256]
    if (tid < 256) red[tid] = sc[tid];
    __syncthreads();
    for (int s = 128; s > 0; s >>= 1) { if (tid < s) red[tid] = fmaxf(red[tid], red[tid + s]); __syncthreads(); }
    float mx = red[0];
    __syncthreads();
    if (tid < 256) { float e = __expf(sc[tid] - mx); sc[tid] = e; red[tid] = e; }
    __syncthreads();
    for (int s = 128; s > 0; s >>= 1) { if (tid < s) red[tid] += red[tid + s]; __syncthreads(); }
    float inv = 1.f / red[0];
    __syncthreads();
    if (tid < 256) wsm[tid] = sc[tid] * inv;
    __syncthreads();

    // weighted sum (vectorized): 4 n-groups x 128 h-groups, then LDS combine
    int hg = tid & 127, ng = tid >> 7;
    const float* hbe = hb + (size_t)(ng * 64) * HD_ + hg * 4;
    float ax = 0.f, ay = 0.f, az = 0.f, aw = 0.f;
    #pragma unroll 8
    for (int n = 0; n < 64; ++n) {
        float4 hv = *(const float4*)(hbe + (size_t)n * HD_);
        float wn = wsm[ng * 64 + n];
        ax += wn * hv.x; ay += wn * hv.y; az += wn * hv.z; aw += wn * hv.w;
    }
    *(float4*)(scratch + ng * 512 + hg * 4) = (float4){ax, ay, az, aw};
    __syncthreads();
    out[(size_t)b * HD_ + tid] =
        scratch[tid] + scratch[512 + tid] + scratch[1024 + tid] + scratch[1536 + tid];
}

// ---------------------------------------------------------------------------
extern "C" void kernel_launch(void* const* d_in, const int* in_sizes, int n_in,
                              void* d_out, int out_size, void* d_ws, size_t ws_size,
                              hipStream_t stream) {
    const float* state = (const float*)d_in[0];
    const float* hints = (const float*)d_in[1];
    const float* Ws    = (const float*)d_in[2];
    const float* bs    = (const float*)d_in[3];
    const float* Wh    = (const float*)d_in[4];
    const float* bh    = (const float*)d_in[5];
    float* out = (float*)d_out;

    float* sn = (float*)d_ws;                              // B
    float* spv = sn + B_;                                  // B*AD
    unsigned short* whp = (unsigned short*)(spv + (size_t)B_ * AD_);  // AD*HD bf16

    k0_pack<<<64, 256, 0, stream>>>(Wh, whp);
    k1_proj<<<B_ / 2, 512, 0, stream>>>(state, Ws, bs, sn, spv);
    k2_fused<<<B_, 512, 0, stream>>>(hints, whp, spv, sn, bh, out);
}

// Round 7
// 153.212 us; speedup vs baseline: 1.8199x; 1.8199x over previous
//
#include <hip/hip_runtime.h>
#include <hip/hip_bf16.h>

typedef __attribute__((ext_vector_type(8))) short bf16x8;
typedef __attribute__((ext_vector_type(4))) float f32x4;

#define B_  512
#define N_  256
#define SD_ 1024
#define HD_ 512
#define AD_ 256

__device__ __forceinline__ unsigned short f2bf(float f) {
    unsigned int u = __float_as_uint(f);
    unsigned int r = (u + 0x7FFFu + ((u >> 16) & 1u)) >> 16;
    return (unsigned short)r;
}

// ---------------------------------------------------------------------------
// K0: pack Wh (AD x HD, f32, row-major) into bf16 B-fragment layout for
// mfma_f32_16x16x32_bf16. Fragment (ct, ks): 64 lanes x 8 bf16 contiguous.
// B[k][col] = Wh[col][k];  col = ct*16 + (lane&15), k = ks*32 + (lane>>4)*8 + i
__global__ void k0_pack(const float* __restrict__ Wh, unsigned short* __restrict__ whp) {
    int g = blockIdx.x * 256 + threadIdx.x;
    int ct  = g >> 10;
    int rem = g & 1023;
    int ks  = rem >> 6;
    int l   = rem & 63;
    int a   = ct * 16 + (l & 15);
    int kb  = ks * 32 + (l >> 4) * 8;
    const float* src = Wh + (size_t)a * HD_ + kb;
    float4 v0 = *(const float4*)(src);
    float4 v1 = *(const float4*)(src + 4);
    bf16x8 o;
    o[0] = (short)f2bf(v0.x); o[1] = (short)f2bf(v0.y);
    o[2] = (short)f2bf(v0.z); o[3] = (short)f2bf(v0.w);
    o[4] = (short)f2bf(v1.x); o[5] = (short)f2bf(v1.y);
    o[6] = (short)f2bf(v1.z); o[7] = (short)f2bf(v1.w);
    ((bf16x8*)whp)[g] = o;
}

// ---------------------------------------------------------------------------
// K1: 2 b's per block, 512 threads. sp = state@Ws^T + bs (coalesced Ws reads),
// sn = max(||sp||,eps).
__global__ __launch_bounds__(512) void k1_proj(
    const float* __restrict__ state, const float* __restrict__ Ws,
    const float* __restrict__ bs,
    float* __restrict__ sn, float* __restrict__ spv)
{
    __shared__ float st[2][SD_];
    __shared__ float spl[2][AD_];
    __shared__ float red[2][AD_];
    int tid = threadIdx.x, lane = tid & 63, w = tid >> 6;
    int b0 = blockIdx.x * 2;
    ((float4*)st)[tid] = ((const float4*)(state + (size_t)b0 * SD_))[tid];
    __syncthreads();
    float4 s0[4], s1[4];
    #pragma unroll
    for (int seg = 0; seg < 4; ++seg) {
        s0[seg] = *(const float4*)&st[0][seg * 256 + lane * 4];
        s1[seg] = *(const float4*)&st[1][seg * 256 + lane * 4];
    }
    #pragma unroll 2
    for (int i = 0; i < 32; ++i) {
        int a = w * 32 + i;
        const float4* wr = (const float4*)(Ws + (size_t)a * SD_);
        float p0 = 0.f, p1 = 0.f;
        #pragma unroll
        for (int seg = 0; seg < 4; ++seg) {
            float4 wv = wr[seg * 64 + lane];
            p0 += wv.x * s0[seg].x + wv.y * s0[seg].y + wv.z * s0[seg].z + wv.w * s0[seg].w;
            p1 += wv.x * s1[seg].x + wv.y * s1[seg].y + wv.z * s1[seg].z + wv.w * s1[seg].w;
        }
        #pragma unroll
        for (int d = 1; d < 64; d <<= 1) { p0 += __shfl_xor(p0, d); p1 += __shfl_xor(p1, d); }
        if (lane == 0) {
            float bsa = bs[a];
            spl[0][a] = p0 + bsa;
            spl[1][a] = p1 + bsa;
        }
    }
    __syncthreads();
    int tb = tid >> 8, t = tid & 255;
    float sv = spl[tb][t];
    spv[(size_t)(b0 + tb) * AD_ + t] = sv;
    red[tb][t] = sv * sv;
    __syncthreads();
    for (int s = 128; s > 0; s >>= 1) { if (t < s) red[tb][t] += red[tb][t + s]; __syncthreads(); }
    if (t == 0) sn[b0 + tb] = fmaxf(sqrtf(red[tb][0]), 1e-8f);
}

// ---------------------------------------------------------------------------
// K2 fused: one block per b (512 threads, 8 waves), 2 blocks/CU.
// BM=64 (4 mc-chunks): steady-state regs = acc 32 + v 16 + frags 12 + misc
// (~90 < 128) -- R4/R5/R6 spilled because BM=128 needed acc 64 + v 32 > cap.
__device__ __forceinline__ void stage_tile(unsigned short* buf, const float4* v,
                                           int rr, int cg) {
    #pragma unroll
    for (int j = 0; j < 4; ++j) {
        int row = j * 16 + rr;
        float4 x = v[j];
        ushort4 u;
        u.x = f2bf(x.x); u.y = f2bf(x.y); u.z = f2bf(x.z); u.w = f2bf(x.w);
        *(ushort4*)((char*)buf + row * 256 + ((cg * 8) ^ ((row & 7) << 4))) = u;
    }
}

__global__ __launch_bounds__(512, 2) void k2_fused(
    const float* __restrict__ hints, const unsigned short* __restrict__ whp,
    const float* __restrict__ spv, const float* __restrict__ sn,
    const float* __restrict__ bh, float* __restrict__ out)
{
    __shared__ __align__(16) char smem[41984];
    unsigned short* A_bf0 = (unsigned short*)smem;            // 16KB (64x128 bf16)
    unsigned short* A_bf1 = (unsigned short*)(smem + 16384);  // 16KB
    float* sp_lds  = (float*)(smem + 32768);                  // 1KB
    float* bh_lds  = (float*)(smem + 33792);                  // 1KB
    float* norm2p  = (float*)(smem + 34816);                  // 8x64 f32 = 2KB
    float* nump    = (float*)(smem + 36864);                  // 2KB
    float* sc      = (float*)(smem + 38912);                  // 1KB
    float* red     = (float*)(smem + 39936);                  // 1KB
    float* wsm     = (float*)(smem + 40960);                  // 1KB
    float* scratch = (float*)smem;                            // epilogue alias (8KB)

    int tid = threadIdx.x, lane = tid & 63, w = tid >> 6;
    int b = blockIdx.x;
    const float* hb = hints + (size_t)b * N_ * HD_;
    if (tid < 64) ((float4*)sp_lds)[tid] = ((const float4*)(spv + (size_t)b * AD_))[tid];
    else if (tid < 128) ((float4*)bh_lds)[tid - 64] = ((const float4*)bh)[tid - 64];
    float snb = sn[b];
    int rr = tid >> 5;        // row sub-index (0..15)
    int cg = tid & 31;        // 16B col-group within 128-col chunk
    int cl = lane & 15;
    const float* hrow = hb + (size_t)rr * HD_ + cg * 4;
    __syncthreads();
    float bh0 = bh_lds[(2 * w + 0) * 16 + cl];
    float bh1 = bh_lds[(2 * w + 1) * 16 + cl];
    float sp0 = sp_lds[(2 * w + 0) * 16 + cl];
    float sp1 = sp_lds[(2 * w + 1) * 16 + cl];

    float4 v[4];
    #pragma unroll
    for (int j = 0; j < 4; ++j)               // mc=0, kc=0
        v[j] = *(const float4*)(hrow + (size_t)(j * 16) * HD_);

    for (int mc = 0; mc < 4; ++mc) {
        f32x4 acc[4][2];
        #pragma unroll
        for (int mf = 0; mf < 4; ++mf) {
            acc[mf][0] = (f32x4){0.f, 0.f, 0.f, 0.f};
            acc[mf][1] = (f32x4){0.f, 0.f, 0.f, 0.f};
        }
        stage_tile(A_bf0, v, rr, cg);
        __syncthreads();

        for (int kc = 0; kc < 4; ++kc) {
            // issue next chunk's loads early (T14: hide HBM under MFMA)
            if (kc < 3) {
                #pragma unroll
                for (int j = 0; j < 4; ++j)
                    v[j] = *(const float4*)(hrow + (size_t)(mc * 64 + j * 16) * HD_ + (kc + 1) * 128);
            }
            const unsigned short* Ab = (kc & 1) ? A_bf1 : A_bf0;
            int kc4 = kc * 4;
            #pragma unroll
            for (int ks = 0; ks < 4; ++ks) {
                bf16x8 bfr0 = ((const bf16x8*)whp)[((2 * w + 0) * 16 + kc4 + ks) * 64 + lane];
                bf16x8 bfr1 = ((const bf16x8*)whp)[((2 * w + 1) * 16 + kc4 + ks) * 64 + lane];
                #pragma unroll
                for (int mf = 0; mf < 4; ++mf) {
                    int r = mf * 16 + cl;
                    bf16x8 afr = *(const bf16x8*)((const char*)Ab + r * 256 +
                                 ((ks * 64 + (lane >> 4) * 16) ^ ((r & 7) << 4)));
                    acc[mf][0] = __builtin_amdgcn_mfma_f32_16x16x32_bf16(afr, bfr0, acc[mf][0], 0, 0, 0);
                    acc[mf][1] = __builtin_amdgcn_mfma_f32_16x16x32_bf16(afr, bfr1, acc[mf][1], 0, 0, 0);
                }
            }
            if (kc < 3) stage_tile((kc & 1) ? A_bf0 : A_bf1, v, rr, cg);
            __syncthreads();
        }

        // norm2 + numerator from acc. C layout: col = ct*16+cl, row = mf*16+(lane>>4)*4+r
        #pragma unroll
        for (int mf = 0; mf < 4; ++mf) {
            #pragma unroll
            for (int r = 0; r < 4; ++r) {
                float h0 = acc[mf][0][r] + bh0;
                float h1 = acc[mf][1][r] + bh1;
                float vv = h0 * h0 + h1 * h1;
                float uu = sp0 * h0 + sp1 * h1;
                vv += __shfl_xor(vv, 1); uu += __shfl_xor(uu, 1);
                vv += __shfl_xor(vv, 2); uu += __shfl_xor(uu, 2);
                vv += __shfl_xor(vv, 4); uu += __shfl_xor(uu, 4);
                vv += __shfl_xor(vv, 8); uu += __shfl_xor(uu, 8);
                if (cl == 0) {
                    int idx = w * 64 + mf * 16 + (lane >> 4) * 4 + r;
                    norm2p[idx] = vv;
                    nump[idx]   = uu;
                }
            }
        }
        // acc dead here; issue next-mc kc=0 loads (overlap sc + barriers)
        if (mc < 3) {
            #pragma unroll
            for (int j = 0; j < 4; ++j)
                v[j] = *(const float4*)(hrow + (size_t)((mc + 1) * 64 + j * 16) * HD_);
        }
        __syncthreads();
        if (tid < 64) {
            float n2 = 0.f, nm = 0.f;
            #pragma unroll
            for (int ww = 0; ww < 8; ++ww) {
                n2 += norm2p[ww * 64 + tid];
                nm += nump[ww * 64 + tid];
            }
            float hn = fmaxf(sqrtf(n2), 1e-8f);
            sc[mc * 64 + tid] = nm / (snb * hn);
        }
        __syncthreads();
    }

    // softmax over sc[256]
    if (tid < 256) red[tid] = sc[tid];
    __syncthreads();
    for (int s = 128; s > 0; s >>= 1) { if (tid < s) red[tid] = fmaxf(red[tid], red[tid + s]); __syncthreads(); }
    float mx = red[0];
    __syncthreads();
    if (tid < 256) { float e = __expf(sc[tid] - mx); sc[tid] = e; red[tid] = e; }
    __syncthreads();
    for (int s = 128; s > 0; s >>= 1) { if (tid < s) red[tid] += red[tid + s]; __syncthreads(); }
    float inv = 1.f / red[0];
    __syncthreads();
    if (tid < 256) wsm[tid] = sc[tid] * inv;
    __syncthreads();

    // weighted sum (vectorized): 4 n-groups x 128 h-groups, then LDS combine
    int hg = tid & 127, ng = tid >> 7;
    const float* hbe = hb + (size_t)(ng * 64) * HD_ + hg * 4;
    float ax = 0.f, ay = 0.f, az = 0.f, aw = 0.f;
    #pragma unroll 8
    for (int n = 0; n < 64; ++n) {
        float4 hv = *(const float4*)(hbe + (size_t)n * HD_);
        float wn = wsm[ng * 64 + n];
        ax += wn * hv.x; ay += wn * hv.y; az += wn * hv.z; aw += wn * hv.w;
    }
    *(float4*)(scratch + ng * 512 + hg * 4) = (float4){ax, ay, az, aw};
    __syncthreads();
    out[(size_t)b * HD_ + tid] =
        scratch[tid] + scratch[512 + tid] + scratch[1024 + tid] + scratch[1536 + tid];
}

// ---------------------------------------------------------------------------
extern "C" void kernel_launch(void* const* d_in, const int* in_sizes, int n_in,
                              void* d_out, int out_size, void* d_ws, size_t ws_size,
                              hipStream_t stream) {
    const float* state = (const float*)d_in[0];
    const float* hints = (const float*)d_in[1];
    const float* Ws    = (const float*)d_in[2];
    const float* bs    = (const float*)d_in[3];
    const float* Wh    = (const float*)d_in[4];
    const float* bh    = (const float*)d_in[5];
    float* out = (float*)d_out;

    float* sn = (float*)d_ws;                              // B
    float* spv = sn + B_;                                  // B*AD
    unsigned short* whp = (unsigned short*)(spv + (size_t)B_ * AD_);  // AD*HD bf16

    k0_pack<<<64, 256, 0, stream>>>(Wh, whp);
    k1_proj<<<B_ / 2, 512, 0, stream>>>(state, Ws, bs, sn, spv);
    k2_fused<<<B_, 512, 0, stream>>>(hints, whp, spv, sn, bh, out);
}

// Round 8
// 147.594 us; speedup vs baseline: 1.8892x; 1.0381x over previous
//
#include <hip/hip_runtime.h>
#include <hip/hip_bf16.h>

typedef __attribute__((ext_vector_type(8))) short bf16x8;
typedef __attribute__((ext_vector_type(4))) float f32x4;

#define B_  512
#define N_  256
#define SD_ 1024
#define HD_ 512
#define AD_ 256

__device__ __forceinline__ unsigned short f2bf(float f) {
    unsigned int u = __float_as_uint(f);
    unsigned int r = (u + 0x7FFFu + ((u >> 16) & 1u)) >> 16;
    return (unsigned short)r;
}

// ---------------------------------------------------------------------------
// K0: pack Wh (AD x HD, f32, row-major) into bf16 B-fragment layout for
// mfma_f32_16x16x32_bf16. Fragment (ct, ks): 64 lanes x 8 bf16 contiguous.
__global__ void k0_pack(const float* __restrict__ Wh, unsigned short* __restrict__ whp) {
    int g = blockIdx.x * 256 + threadIdx.x;
    int ct  = g >> 10;
    int rem = g & 1023;
    int ks  = rem >> 6;
    int l   = rem & 63;
    int a   = ct * 16 + (l & 15);
    int kb  = ks * 32 + (l >> 4) * 8;
    const float* src = Wh + (size_t)a * HD_ + kb;
    float4 v0 = *(const float4*)(src);
    float4 v1 = *(const float4*)(src + 4);
    bf16x8 o;
    o[0] = (short)f2bf(v0.x); o[1] = (short)f2bf(v0.y);
    o[2] = (short)f2bf(v0.z); o[3] = (short)f2bf(v0.w);
    o[4] = (short)f2bf(v1.x); o[5] = (short)f2bf(v1.y);
    o[6] = (short)f2bf(v1.z); o[7] = (short)f2bf(v1.w);
    ((bf16x8*)whp)[g] = o;
}

// ---------------------------------------------------------------------------
// K1: 2 b's per block, 512 threads. sp = state@Ws^T + bs (coalesced Ws reads),
// sn = max(||sp||,eps).
__global__ __launch_bounds__(512) void k1_proj(
    const float* __restrict__ state, const float* __restrict__ Ws,
    const float* __restrict__ bs,
    float* __restrict__ sn, float* __restrict__ spv)
{
    __shared__ float st[2][SD_];
    __shared__ float spl[2][AD_];
    __shared__ float red[2][AD_];
    int tid = threadIdx.x, lane = tid & 63, w = tid >> 6;
    int b0 = blockIdx.x * 2;
    ((float4*)st)[tid] = ((const float4*)(state + (size_t)b0 * SD_))[tid];
    __syncthreads();
    float4 s0[4], s1[4];
    #pragma unroll
    for (int seg = 0; seg < 4; ++seg) {
        s0[seg] = *(const float4*)&st[0][seg * 256 + lane * 4];
        s1[seg] = *(const float4*)&st[1][seg * 256 + lane * 4];
    }
    #pragma unroll 2
    for (int i = 0; i < 32; ++i) {
        int a = w * 32 + i;
        const float4* wr = (const float4*)(Ws + (size_t)a * SD_);
        float p0 = 0.f, p1 = 0.f;
        #pragma unroll
        for (int seg = 0; seg < 4; ++seg) {
            float4 wv = wr[seg * 64 + lane];
            p0 += wv.x * s0[seg].x + wv.y * s0[seg].y + wv.z * s0[seg].z + wv.w * s0[seg].w;
            p1 += wv.x * s1[seg].x + wv.y * s1[seg].y + wv.z * s1[seg].z + wv.w * s1[seg].w;
        }
        #pragma unroll
        for (int d = 1; d < 64; d <<= 1) { p0 += __shfl_xor(p0, d); p1 += __shfl_xor(p1, d); }
        if (lane == 0) {
            float bsa = bs[a];
            spl[0][a] = p0 + bsa;
            spl[1][a] = p1 + bsa;
        }
    }
    __syncthreads();
    int tb = tid >> 8, t = tid & 255;
    float sv = spl[tb][t];
    spv[(size_t)(b0 + tb) * AD_ + t] = sv;
    red[tb][t] = sv * sv;
    __syncthreads();
    for (int s = 128; s > 0; s >>= 1) { if (t < s) red[tb][t] += red[tb][t + s]; __syncthreads(); }
    if (t == 0) sn[b0 + tb] = fmaxf(sqrtf(red[tb][0]), 1e-8f);
}

// ---------------------------------------------------------------------------
// K2 fused: one block per b (512 threads, 8 waves), 2 blocks/CU.
// BM=64, BK=128, 16 flat phases p = mc*4+kc. Depth-2 prefetch, TRIPLE-buffer
// LDS (T3/T4): at phase p issue L[p+2], MFMA buf[p%3], stage L[p+1] (loaded a
// full phase ago -> HBM latency hidden; stage's wait is a counted vmcnt(4),
// so L[p+2] stays in flight across the barrier -- queue never drains).
// Swizzle (row&15)<<4 is bijective over the 256B LDS row (R7's (row&7) left
// rows r/r+8 on the same bank: 4.2M conflicts).
__device__ __forceinline__ void stage_tile(unsigned short* buf, const float4* v,
                                           int rr, int cg) {
    #pragma unroll
    for (int j = 0; j < 4; ++j) {
        int row = j * 16 + rr;
        float4 x = v[j];
        ushort4 u;
        u.x = f2bf(x.x); u.y = f2bf(x.y); u.z = f2bf(x.z); u.w = f2bf(x.w);
        *(ushort4*)((char*)buf + row * 256 + ((cg * 8) ^ ((row & 15) << 4))) = u;
    }
}

__global__ __launch_bounds__(512, 2) void k2_fused(
    const float* __restrict__ hints, const unsigned short* __restrict__ whp,
    const float* __restrict__ spv, const float* __restrict__ sn,
    const float* __restrict__ bh, float* __restrict__ out)
{
    __shared__ __align__(16) char smem[58368];
    unsigned short* buf0 = (unsigned short*)smem;             // 16KB
    unsigned short* buf1 = (unsigned short*)(smem + 16384);   // 16KB
    unsigned short* buf2 = (unsigned short*)(smem + 32768);   // 16KB
    float* sp_lds  = (float*)(smem + 49152);                  // 1KB
    float* bh_lds  = (float*)(smem + 50176);                  // 1KB
    float* norm2p  = (float*)(smem + 51200);                  // 2KB
    float* nump    = (float*)(smem + 53248);                  // 2KB
    float* sc      = (float*)(smem + 55296);                  // 1KB
    float* red     = (float*)(smem + 56320);                  // 1KB
    float* wsm     = (float*)(smem + 57344);                  // 1KB
    float* scratch = (float*)smem;                            // epilogue alias

    int tid = threadIdx.x, lane = tid & 63, w = tid >> 6;
    int b = blockIdx.x;
    const float* hb = hints + (size_t)b * N_ * HD_;
    if (tid < 64) ((float4*)sp_lds)[tid] = ((const float4*)(spv + (size_t)b * AD_))[tid];
    else if (tid < 128) ((float4*)bh_lds)[tid - 64] = ((const float4*)bh)[tid - 64];
    float snb = sn[b];
    int rr = tid >> 5;        // row sub-index (0..15)
    int cg = tid & 31;        // 16B col-group within 128-col chunk
    int cl = lane & 15;
    const float* hrow = hb + (size_t)rr * HD_ + cg * 4;
    __syncthreads();
    float bh0 = bh_lds[(2 * w + 0) * 16 + cl];
    float bh1 = bh_lds[(2 * w + 1) * 16 + cl];
    float sp0 = sp_lds[(2 * w + 0) * 16 + cl];
    float sp1 = sp_lds[(2 * w + 1) * 16 + cl];

    // L[p] address: row block (p>>2)*64 + j*16, col chunk (p&3)*128
#define LADDR(p, j) (hrow + (size_t)(((p) >> 2) * 64 + (j) * 16) * HD_ + ((p) & 3) * 128)

    float4 va[4], vb[4];
    #pragma unroll
    for (int j = 0; j < 4; ++j) va[j] = *(const float4*)LADDR(0, j);
    #pragma unroll
    for (int j = 0; j < 4; ++j) vb[j] = *(const float4*)LADDR(1, j);
    stage_tile(buf0, va, rr, cg);
    __syncthreads();
    unsigned short *bufR = buf0, *bufW = buf1, *bufS = buf2;

    for (int mc = 0; mc < 4; ++mc) {
        f32x4 acc[4][2];
        #pragma unroll
        for (int mf = 0; mf < 4; ++mf) {
            acc[mf][0] = (f32x4){0.f, 0.f, 0.f, 0.f};
            acc[mf][1] = (f32x4){0.f, 0.f, 0.f, 0.f};
        }
        #pragma unroll
        for (int kc = 0; kc < 4; ++kc) {
            int p = mc * 4 + kc;
            // A: issue L[p+2] (parity (p+2)&1 == kc&1: even->va, odd->vb)
            if (p + 2 < 16) {
                if ((kc & 1) == 0) {
                    #pragma unroll
                    for (int j = 0; j < 4; ++j) va[j] = *(const float4*)LADDR(p + 2, j);
                } else {
                    #pragma unroll
                    for (int j = 0; j < 4; ++j) vb[j] = *(const float4*)LADDR(p + 2, j);
                }
            }
            // B: MFMA on bufR
            #pragma unroll
            for (int ks = 0; ks < 4; ++ks) {
                bf16x8 bfr0 = ((const bf16x8*)whp)[((2 * w + 0) * 16 + kc * 4 + ks) * 64 + lane];
                bf16x8 bfr1 = ((const bf16x8*)whp)[((2 * w + 1) * 16 + kc * 4 + ks) * 64 + lane];
                #pragma unroll
                for (int mf = 0; mf < 4; ++mf) {
                    int r = mf * 16 + cl;
                    bf16x8 afr = *(const bf16x8*)((const char*)bufR + r * 256 +
                                 ((ks * 64 + (lane >> 4) * 16) ^ ((r & 15) << 4)));
                    acc[mf][0] = __builtin_amdgcn_mfma_f32_16x16x32_bf16(afr, bfr0, acc[mf][0], 0, 0, 0);
                    acc[mf][1] = __builtin_amdgcn_mfma_f32_16x16x32_bf16(afr, bfr1, acc[mf][1], 0, 0, 0);
                }
            }
            // C: stage L[p+1] (parity (p+1)&1: kc even -> vb, kc odd -> va)
            if (p + 1 < 16) stage_tile(bufW, (kc & 1) ? va : vb, rr, cg);
            // D: barrier + rotate
            __syncthreads();
            unsigned short* t0 = bufR; bufR = bufW; bufW = bufS; bufS = t0;
        }

        // norm2 + numerator from acc. C layout: col = ct*16+cl, row = mf*16+(lane>>4)*4+r
        #pragma unroll
        for (int mf = 0; mf < 4; ++mf) {
            #pragma unroll
            for (int r = 0; r < 4; ++r) {
                float h0 = acc[mf][0][r] + bh0;
                float h1 = acc[mf][1][r] + bh1;
                float vv = h0 * h0 + h1 * h1;
                float uu = sp0 * h0 + sp1 * h1;
                vv += __shfl_xor(vv, 1); uu += __shfl_xor(uu, 1);
                vv += __shfl_xor(vv, 2); uu += __shfl_xor(uu, 2);
                vv += __shfl_xor(vv, 4); uu += __shfl_xor(uu, 4);
                vv += __shfl_xor(vv, 8); uu += __shfl_xor(uu, 8);
                if (cl == 0) {
                    int idx = w * 64 + mf * 16 + (lane >> 4) * 4 + r;
                    norm2p[idx] = vv;
                    nump[idx]   = uu;
                }
            }
        }
        __syncthreads();
        if (tid < 64) {
            float n2 = 0.f, nm = 0.f;
            #pragma unroll
            for (int ww = 0; ww < 8; ++ww) {
                n2 += norm2p[ww * 64 + tid];
                nm += nump[ww * 64 + tid];
            }
            float hn = fmaxf(sqrtf(n2), 1e-8f);
            sc[mc * 64 + tid] = nm / (snb * hn);
        }
        __syncthreads();
    }
#undef LADDR

    // softmax over sc[256]
    if (tid < 256) red[tid] = sc[tid];
    __syncthreads();
    for (int s = 128; s > 0; s >>= 1) { if (tid < s) red[tid] = fmaxf(red[tid], red[tid + s]); __syncthreads(); }
    float mx = red[0];
    __syncthreads();
    if (tid < 256) { float e = __expf(sc[tid] - mx); sc[tid] = e; red[tid] = e; }
    __syncthreads();
    for (int s = 128; s > 0; s >>= 1) { if (tid < s) red[tid] += red[tid + s]; __syncthreads(); }
    float inv = 1.f / red[0];
    __syncthreads();
    if (tid < 256) wsm[tid] = sc[tid] * inv;
    __syncthreads();

    // weighted sum (vectorized): 4 n-groups x 128 h-groups, then LDS combine
    int hg = tid & 127, ng = tid >> 7;
    const float* hbe = hb + (size_t)(ng * 64) * HD_ + hg * 4;
    float ax = 0.f, ay = 0.f, az = 0.f, aw = 0.f;
    #pragma unroll 8
    for (int n = 0; n < 64; ++n) {
        float4 hv = *(const float4*)(hbe + (size_t)n * HD_);
        float wn = wsm[ng * 64 + n];
        ax += wn * hv.x; ay += wn * hv.y; az += wn * hv.z; aw += wn * hv.w;
    }
    *(float4*)(scratch + ng * 512 + hg * 4) = (float4){ax, ay, az, aw};
    __syncthreads();
    out[(size_t)b * HD_ + tid] =
        scratch[tid] + scratch[512 + tid] + scratch[1024 + tid] + scratch[1536 + tid];
}

// ---------------------------------------------------------------------------
extern "C" void kernel_launch(void* const* d_in, const int* in_sizes, int n_in,
                              void* d_out, int out_size, void* d_ws, size_t ws_size,
                              hipStream_t stream) {
    const float* state = (const float*)d_in[0];
    const float* hints = (const float*)d_in[1];
    const float* Ws    = (const float*)d_in[2];
    const float* bs    = (const float*)d_in[3];
    const float* Wh    = (const float*)d_in[4];
    const float* bh    = (const float*)d_in[5];
    float* out = (float*)d_out;

    float* sn = (float*)d_ws;                              // B
    float* spv = sn + B_;                                  // B*AD
    unsigned short* whp = (unsigned short*)(spv + (size_t)B_ * AD_);  // AD*HD bf16

    k0_pack<<<64, 256, 0, stream>>>(Wh, whp);
    k1_proj<<<B_ / 2, 512, 0, stream>>>(state, Ws, bs, sn, spv);
    k2_fused<<<B_, 512, 0, stream>>>(hints, whp, spv, sn, bh, out);
}